// Round 11
// baseline (168.198 us; speedup 1.0000x reference)
//
#include <hip/hip_runtime.h>

#define S_ROWS 524288
#define D_COLS 63
#define BLOCK 256
#define GRID 1024                 // 4096 waves x 128 rows each
#define ROWS_PER_WAVE 128
#define ITERS 16                  // 8 rows per iteration
#define NACC 30
#define POSW 0.2f
#define NEG_INF (-__builtin_huge_valf())

#define F_CUB  1u
#define F_CUB2 2u
#define F_AP   4u
#define F_REF  8u
#define F_TR   16u
#define F_SQ   32u

enum {
  A_CMD_LOSS = 0, A_CMDC, A_MAE1, A_MAE2, A_MAE4, A_MAE5,
  A_CE_AP, A_CUBC,
  A_REF_AX_CE, A_REF_CUB_CE, A_REF_AXC, A_REF_CUBC,
  A_TR_AX_CE, A_TR_CUB_CE, A_TR_AXC, A_TR_CUBC,
  A_SQ_CUB_CE, A_FACE_CE, A_SQ_CUBC, A_FACEC,
  A_BCE, A_NPOS, A_NNEG, A_POSC, A_NEGC,
  A_NA, A_NC, A_NREF, A_NTR, A_NSQ
};

__device__ __forceinline__ float logsig(float x) {
  float ax = fabsf(x);
  return fminf(x, 0.f) - __logf(1.f + __expf(-ax));
}

__global__ void init_ws(float* ws) {
  int i = threadIdx.x;
  if (i < NACC) ws[i] = 0.f;
  unsigned* wu = (unsigned*)ws;
  if (i == NACC) wu[NACC] = 0xFFFFFFFFu;
  if (i == NACC + 1) wu[NACC + 1] = 0u;
}

__launch_bounds__(BLOCK, 4)
__global__ void prog_loss_main(const float* __restrict__ P,
                               const float* __restrict__ T,
                               const float* __restrict__ W,
                               float* __restrict__ ws) {
  __shared__ float sred[4][NACC];
  __shared__ unsigned sflags[4];
  __shared__ unsigned smin[4];

  const int tid = threadIdx.x;
  const int lane = tid & 63;
  const int wave = tid >> 6;
  const int k = lane & 7;   // slice-lane within row
  const int g = lane >> 3;  // row within 8-row group
  const int wid = blockIdx.x * 4 + wave;

  // per-lane loop-invariant slice geometry (cndmask chains, no arrays)
  const int st = (k == 0) ? 0 : (k == 1) ? 7 : (k == 2) ? 18 : (k == 3) ? 29
               : (k == 4) ? 40 : (k == 5) ? 49 : (k == 6) ? 54 : 62;
  const int ln = (k == 0) ? 7 : (k == 1) ? 11 : (k == 2) ? 11 : (k == 3) ? 11
               : (k == 4) ? 9 : (k == 5) ? 5 : (k == 6) ? 8 : 1;
  const int cl = (k == 0) ? 7 : (k == 1) ? 11 : (k == 2) ? 11 : (k == 3) ? 11
               : (k == 4) ? 0 : (k == 5) ? 3 : (k == 6) ? 6 : 0;
  float cem[11];  // compile-time-indexed only
  #pragma unroll
  for (int j = 0; j < 11; ++j) cem[j] = (j < cl) ? 0.f : NEG_INF;

  float acc[NACC];
  #pragma unroll
  for (int v = 0; v < NACC; ++v) acc[v] = 0.f;
  unsigned fl = 0u;
  unsigned mymin = 0xFFFFFFFFu;

  #pragma unroll 1
  for (int it = 0; it < ITERS; ++it) {
    const int row = wid * ROWS_PER_WAVE + it * 8 + g;
    const size_t rb = (size_t)row * D_COLS + st;

    // BOUNDS-SAFE: only load the ln elements this lane owns (exec-masked
    // per element); max touched index = row*63 + st + ln - 1 <= row*63 + 62.
    float pv[11], tv[11], wv[11];
    #pragma unroll
    for (int j = 0; j < 11; ++j) {
      if (j < ln) {
        pv[j] = P[rb + j];
        tv[j] = T[rb + j];
        wv[j] = W[rb + j];
      } else {
        pv[j] = 0.f; tv[j] = 0.f; wv[j] = 0.f;
      }
    }

    // lane-local scans over the CE sub-range (masked by cem = 0 / -INF)
    float tmax = NEG_INF, pmax = NEG_INF, p_at = 0.f;
    int targ = -1, pidx = -1;
    #pragma unroll
    for (int j = 0; j < 11; ++j) {
      float te = tv[j] + cem[j];
      bool u = te > tmax;
      tmax = u ? te : tmax;
      targ = u ? j : targ;
      p_at = u ? pv[j] : p_at;
      float pe = pv[j] + cem[j];
      bool v2 = pe > pmax;
      pmax = v2 ? pe : pmax;
      pidx = v2 ? j : pidx;
    }
    float s = 0.f;
    #pragma unroll
    for (int j = 0; j < 11; ++j) s += __expf(pv[j] + cem[j] - pmax);
    float ce = pmax + __logf(s) - p_at;
    int ok = (pidx == targ) ? 1 : 0;

    // lane-local masked MAE over the full owned range
    float mae = 0.f;
    #pragma unroll
    for (int j = 0; j < 11; ++j) {
      float we = (j < ln) ? wv[j] : 0.f;
      mae = fmaf(we, fabsf(pv[j] - tv[j]), mae);
    }

    // tiny cross-lane glue within the 8-lane row group
    int c   = __shfl(targ, 0, 8);   // command (k0's t-argmax, st=0 -> absolute)
    int okC = __shfl(ok, 2, 8);
    int okD = __shfl(ok, 3, 8);
    const unsigned gr = (unsigned)row;

    // MAE buckets (every lane owns disjoint cols of the row)
    acc[A_MAE1] += (c == 1) ? mae : 0.f;
    acc[A_MAE2] += (c == 2) ? mae : 0.f;
    acc[A_MAE4] += (c == 4) ? mae : 0.f;
    acc[A_MAE5] += (c == 5) ? mae : 0.f;

    if (k == 0) {
      acc[A_CMD_LOSS] += ce;
      acc[A_CMDC] += ok ? 1.f : 0.f;
      if (c == 1) {
        acc[A_NC] += 1.f;
        if (gr >= 1u) fl |= F_CUB;
        if (gr >= 2u) fl |= F_CUB2;
        mymin = (gr < mymin) ? gr : mymin;
      } else if (c == 2) { acc[A_NA] += 1.f; if (gr >= 1u) fl |= F_AP; }
      else if (c == 3) { acc[A_NREF] += 1.f; if (gr >= 1u) fl |= F_REF; }
      else if (c == 4) { acc[A_NTR] += 1.f; if (gr >= 1u) fl |= F_TR; }
      else if (c == 5) { acc[A_NSQ] += 1.f; if (gr >= 1u) fl |= F_SQ; }
    } else if (k == 1) {
      if (c == 2)      { acc[A_CE_AP] += ce; acc[A_CUBC] += (ok && okC) ? 1.f : 0.f; }
      else if (c == 3) { acc[A_REF_CUB_CE] += ce; acc[A_REF_CUBC] += ok ? 1.f : 0.f; }
      else if (c == 4) { acc[A_TR_CUB_CE]  += ce; acc[A_TR_CUBC]  += ok ? 1.f : 0.f; }
      else if (c == 5) { acc[A_SQ_CUB_CE] += ce; acc[A_SQ_CUBC] += (ok && okC && okD) ? 1.f : 0.f; }
    } else if (k == 2) {
      if (c == 2)      acc[A_CE_AP] += ce;
      else if (c == 5) acc[A_SQ_CUB_CE] += ce;
    } else if (k == 3) {
      if (c == 5) acc[A_SQ_CUB_CE] += ce;
    } else if (k == 5) {
      if (c == 3)      { acc[A_REF_AX_CE] += ce; acc[A_REF_AXC] += ok ? 1.f : 0.f; }
      else if (c == 4) { acc[A_TR_AX_CE]  += ce; acc[A_TR_AXC]  += ok ? 1.f : 0.f; }
    } else if (k == 6) {
      if (c == 5) { acc[A_FACE_CE] += ce; acc[A_FACEC] += ok ? 1.f : 0.f; }
    } else if (k == 7) {
      if (c == 1) {
        float x62 = pv[0], t62 = tv[0];
        float bce = -(POSW * t62 * logsig(x62) + (1.f - t62) * logsig(-x62));
        acc[A_BCE] += bce;
        bool pos = (t62 == 1.f), neg = (t62 == 0.f);
        acc[A_NPOS] += pos ? 1.f : 0.f;
        acc[A_NNEG] += neg ? 1.f : 0.f;
        acc[A_POSC] += (pos && x62 > 0.f) ? 1.f : 0.f;
        acc[A_NEGC] += (neg && x62 <= 0.f) ? 1.f : 0.f;
      }
    }
  }

  // ---- reduction: wave shuffle -> LDS -> atomics ----
  #pragma unroll
  for (int v = 0; v < NACC; ++v) {
    float x = acc[v];
    #pragma unroll
    for (int off = 32; off > 0; off >>= 1) x += __shfl_down(x, off, 64);
    if (lane == 0) sred[wave][v] = x;
  }
  {
    unsigned f = fl, m = mymin;
    #pragma unroll
    for (int off = 32; off > 0; off >>= 1) {
      f |= __shfl_down(f, off, 64);
      unsigned om = __shfl_down(m, off, 64);
      m = (om < m) ? om : m;
    }
    if (lane == 0) { sflags[wave] = f; smin[wave] = m; }
  }
  __syncthreads();
  unsigned* wu = (unsigned*)ws;
  if (tid == 0) {
    unsigned f = sflags[0] | sflags[1] | sflags[2] | sflags[3];
    unsigned m = min(min(smin[0], smin[1]), min(smin[2], smin[3]));
    if (f) atomicOr(&wu[NACC + 1], f);
    if (m != 0xFFFFFFFFu) atomicMin(&wu[NACC], m);
  }
  if (tid < NACC) {
    float s = sred[0][tid] + sred[1][tid] + sred[2][tid] + sred[3][tid];
    if (s != 0.f) atomicAdd(&ws[tid], s);
  }
}

__global__ void finalize_k(const float* __restrict__ ws,
                           const float* __restrict__ P,
                           const float* __restrict__ T,
                           float* __restrict__ out) {
  const unsigned* wu = (const unsigned*)ws;
  unsigned flags = wu[NACC + 1];
  unsigned fm = wu[NACC];
  bool g_cub  = (flags & F_CUB)  != 0;
  bool g_cub2 = (flags & F_CUB2) != 0;
  bool g_ap   = (flags & F_AP)   != 0;
  bool g_ref  = (flags & F_REF)  != 0;
  bool g_tr   = (flags & F_TR)   != 0;
  bool g_sq   = (flags & F_SQ)   != 0;
  unsigned first = (fm == 0xFFFFFFFFu) ? 0u : fm;
  float x62 = P[(size_t)first * D_COLS + 62];
  float t62 = T[(size_t)first * D_COLS + 62];
  float bce_f = -(POSW * t62 * logsig(x62) + (1.f - t62) * logsig(-x62));
  float pos_f  = (t62 == 1.f) ? 1.f : 0.f;
  float neg_f  = (t62 == 0.f) ? 1.f : 0.f;
  float posc_f = (t62 == 1.f && x62 > 0.f) ? 1.f : 0.f;
  float negc_f = (t62 == 0.f && x62 <= 0.f) ? 1.f : 0.f;

  out[0]  = ws[A_CMD_LOSS];
  out[1]  = g_cub ? ws[A_MAE1] : 0.f;
  out[2]  = g_ap  ? ws[A_MAE2] : 0.f;
  out[3]  = g_sq  ? ws[A_MAE5] : 0.f;
  out[4]  = g_tr  ? ws[A_MAE4] : 0.f;
  out[5]  = g_ap  ? ws[A_CE_AP] : 0.f;
  out[6]  = g_sq  ? ws[A_SQ_CUB_CE] : 0.f;
  out[7]  = (g_ref ? ws[A_REF_CUB_CE] : 0.f) + (g_tr ? ws[A_TR_CUB_CE] : 0.f);
  out[8]  = (g_ref ? ws[A_REF_AX_CE]  : 0.f) + (g_tr ? ws[A_TR_AX_CE]  : 0.f);
  out[9]  = g_sq ? ws[A_FACE_CE] : 0.f;
  out[10] = ws[A_CMDC];
  out[11] = g_ap ? ws[A_CUBC] : 0.f;
  out[12] = g_sq ? ws[A_SQ_CUBC] : 0.f;
  out[13] = (g_ref ? ws[A_REF_CUBC] : 0.f) + (g_tr ? ws[A_TR_CUBC] : 0.f);
  out[14] = (g_ref ? ws[A_REF_AXC]  : 0.f) + (g_tr ? ws[A_TR_AXC]  : 0.f);
  out[15] = g_sq ? ws[A_FACEC] : 0.f;
  out[16] = g_cub2 ? (ws[A_BCE]  - bce_f)  : 0.f;
  out[17] = g_cub2 ? (ws[A_POSC] - posc_f) : 0.f;
  out[18] = g_cub2 ? (ws[A_NEGC] - negc_f) : 0.f;
  out[19] = g_cub2 ? (ws[A_NNEG] - neg_f)  : 0.f;
  out[20] = g_cub2 ? (ws[A_NPOS] - pos_f)  : 0.f;
  out[21] = ws[A_NA];
  out[22] = ws[A_NC];
  out[23] = ws[A_NREF] + ws[A_NTR];
  out[24] = ws[A_NSQ];
}

extern "C" void kernel_launch(void* const* d_in, const int* in_sizes, int n_in,
                              void* d_out, int out_size, void* d_ws, size_t ws_size,
                              hipStream_t stream) {
  const float* P = (const float*)d_in[0];
  const float* T = (const float*)d_in[1];
  const float* W = (const float*)d_in[2];
  float* ws = (float*)d_ws;
  float* out = (float*)d_out;

  hipLaunchKernelGGL(init_ws, dim3(1), dim3(64), 0, stream, ws);
  hipLaunchKernelGGL(prog_loss_main, dim3(GRID), dim3(BLOCK), 0, stream, P, T, W, ws);
  hipLaunchKernelGGL(finalize_k, dim3(1), dim3(1), 0, stream, ws, P, T, out);
}

// Round 12
// 131.740 us; speedup vs baseline: 1.2767x; 1.2767x over previous
//
#include <hip/hip_runtime.h>

#define S_ROWS 524288
#define D_COLS 63
#define BLOCK 256
#define GRID 1024                 // 4096 waves x 128 rows
#define ROWS_PER_WAVE 128
#define ITERS 16                  // 8 rows per iteration per wave
#define BUF_F4 132                // 528 floats/array/buffer (max read idx 513)
#define NACC 30
#define POSW 0.2f
#define NEG_INF (-__builtin_huge_valf())

#define F_CUB  1u
#define F_CUB2 2u
#define F_AP   4u
#define F_REF  8u
#define F_TR   16u
#define F_SQ   32u

enum {
  A_CMD_LOSS = 0, A_CMDC, A_MAE1, A_MAE2, A_MAE4, A_MAE5,
  A_CE_AP, A_CUBC,
  A_REF_AX_CE, A_REF_CUB_CE, A_REF_AXC, A_REF_CUBC,
  A_TR_AX_CE, A_TR_CUB_CE, A_TR_AXC, A_TR_CUBC,
  A_SQ_CUB_CE, A_FACE_CE, A_SQ_CUBC, A_FACEC,
  A_BCE, A_NPOS, A_NNEG, A_POSC, A_NEGC,
  A_NA, A_NC, A_NREF, A_NTR, A_NSQ
};

#define GLOAD_LDS16(gptr, lptr) \
  __builtin_amdgcn_global_load_lds( \
      (const __attribute__((address_space(1))) void*)(gptr), \
      (__attribute__((address_space(3))) void*)(lptr), 16, 0, 0)

__device__ __forceinline__ float logsig(float x) {
  float ax = fabsf(x);
  return fminf(x, 0.f) - __logf(1.f + __expf(-ax));
}

__global__ void init_ws(float* ws) {
  int i = threadIdx.x;
  if (i < NACC) ws[i] = 0.f;
  unsigned* wu = (unsigned*)ws;
  if (i == NACC) wu[NACC] = 0xFFFFFFFFu;
  if (i == NACC + 1) wu[NACC + 1] = 0u;
}

__launch_bounds__(BLOCK, 3)
__global__ void prog_loss_main(const float* __restrict__ P,
                               const float* __restrict__ T,
                               const float* __restrict__ W,
                               float* __restrict__ ws) {
  // wave-private double-buffered 8-row tiles: [wave][buf][array P/T/W][f4]
  __shared__ float4 sbuf[4][2][3][BUF_F4];
  __shared__ float sred[4][NACC];
  __shared__ unsigned sflags[4];
  __shared__ unsigned smin[4];

  const int tid = threadIdx.x;
  const int lane = tid & 63;
  const int wave = tid >> 6;
  const int k = lane & 7;   // slice-lane within row
  const int g = lane >> 3;  // row within the 8-row group
  const int wid = blockIdx.x * 4 + wave;

  // per-lane slice geometry (wave-uniform code, lane-varying constants)
  const int st = (k == 0) ? 0 : (k == 1) ? 7 : (k == 2) ? 18 : (k == 3) ? 29
               : (k == 4) ? 40 : (k == 5) ? 49 : (k == 6) ? 54 : 62;
  const int ln = (k == 0) ? 7 : (k == 1) ? 11 : (k == 2) ? 11 : (k == 3) ? 11
               : (k == 4) ? 9 : (k == 5) ? 5 : (k == 6) ? 8 : 1;
  const int cl = (k == 0) ? 7 : (k == 1) ? 11 : (k == 2) ? 11 : (k == 3) ? 11
               : (k == 4) ? 0 : (k == 5) ? 3 : (k == 6) ? 6 : 0;
  const int idx0 = g * D_COLS + st;   // float index into the 8-row LDS tile

  float acc[NACC];
  #pragma unroll
  for (int v = 0; v < NACC; ++v) acc[v] = 0.f;
  unsigned fl = 0u;
  unsigned mymin = 0xFFFFFFFFu;

  // ---- wave-private staging: 6 x global_load_lds (f4-coalesced, 1KB/instr) ----
  auto stage = [&](int b, int it) {
    const size_t f4b = (size_t)wid * 2016 + (size_t)it * 126;  // (row0*63)/4
    const float4* P4 = (const float4*)P + f4b;
    const float4* T4 = (const float4*)T + f4b;
    const float4* W4 = (const float4*)W + f4b;
    float4* bp = &sbuf[wave][b][0][0];
    float4* bt = &sbuf[wave][b][1][0];
    float4* bw = &sbuf[wave][b][2][0];
    GLOAD_LDS16(&P4[lane], bp);
    GLOAD_LDS16(&T4[lane], bt);
    GLOAD_LDS16(&W4[lane], bw);
    if (lane < 62) {
      GLOAD_LDS16(&P4[64 + lane], bp + 64);
      GLOAD_LDS16(&T4[64 + lane], bt + 64);
      GLOAD_LDS16(&W4[64 + lane], bw + 64);
    }
  };

  stage(0, 0);  // prologue

  #pragma unroll 1
  for (int it = 0; it < ITERS; ++it) {
    const int b = it & 1;
    if (it + 1 < ITERS) {
      stage(b ^ 1, it + 1);
      asm volatile("s_waitcnt vmcnt(6)" ::: "memory");  // current tile ready; next in flight
    } else {
      asm volatile("s_waitcnt vmcnt(0)" ::: "memory");
    }
    __builtin_amdgcn_sched_barrier(0);

    const float* lp = (const float*)&sbuf[wave][b][0][0];
    const float* lt = (const float*)&sbuf[wave][b][1][0];
    const float* lw = (const float*)&sbuf[wave][b][2][0];

    // unconditional LDS reads (padded buffer); garbage tail is select-masked
    float pv[11], tv[11], wv[11];
    #pragma unroll
    for (int j = 0; j < 11; ++j) {
      pv[j] = lp[idx0 + j];
      tv[j] = lt[idx0 + j];
      wv[j] = lw[idx0 + j];
    }

    // lane-local CE scan, NaN-safe select masking (j < cl)
    float tmax = NEG_INF, pmax = NEG_INF, p_at = 0.f;
    int targ = -1, pidx = -1;
    #pragma unroll
    for (int j = 0; j < 11; ++j) {
      float te = (j < cl) ? tv[j] : NEG_INF;
      float pe = (j < cl) ? pv[j] : NEG_INF;
      bool u = te > tmax;
      tmax = u ? te : tmax;
      targ = u ? j : targ;
      p_at = u ? pv[j] : p_at;
      bool v2 = pe > pmax;
      pmax = v2 ? pe : pmax;
      pidx = v2 ? j : pidx;
    }
    float s = 0.f;
    #pragma unroll
    for (int j = 0; j < 11; ++j) {
      float e = __expf(pv[j] - pmax);
      s += (j < cl) ? e : 0.f;
    }
    float ce = pmax + __logf(s) - p_at;
    int ok = (pidx == targ) ? 1 : 0;

    // lane-local masked MAE (j < ln), product selected before accumulate
    float mae = 0.f;
    #pragma unroll
    for (int j = 0; j < 11; ++j) {
      float d = wv[j] * fabsf(pv[j] - tv[j]);
      mae += (j < ln) ? d : 0.f;
    }

    // cross-lane glue within the 8-lane row group
    int c   = __shfl(targ, 0, 8);   // command (k0's t-argmax, absolute)
    int okC = __shfl(ok, 2, 8);
    int okD = __shfl(ok, 3, 8);
    const int row = wid * ROWS_PER_WAVE + it * 8 + g;
    const unsigned gr = (unsigned)row;

    acc[A_MAE1] += (c == 1) ? mae : 0.f;
    acc[A_MAE2] += (c == 2) ? mae : 0.f;
    acc[A_MAE4] += (c == 4) ? mae : 0.f;
    acc[A_MAE5] += (c == 5) ? mae : 0.f;

    if (k == 0) {
      acc[A_CMD_LOSS] += ce;
      acc[A_CMDC] += ok ? 1.f : 0.f;
      if (c == 1) {
        acc[A_NC] += 1.f;
        if (gr >= 1u) fl |= F_CUB;
        if (gr >= 2u) fl |= F_CUB2;
        mymin = (gr < mymin) ? gr : mymin;
      } else if (c == 2) { acc[A_NA] += 1.f; if (gr >= 1u) fl |= F_AP; }
      else if (c == 3) { acc[A_NREF] += 1.f; if (gr >= 1u) fl |= F_REF; }
      else if (c == 4) { acc[A_NTR] += 1.f; if (gr >= 1u) fl |= F_TR; }
      else if (c == 5) { acc[A_NSQ] += 1.f; if (gr >= 1u) fl |= F_SQ; }
    } else if (k == 1) {
      if (c == 2)      { acc[A_CE_AP] += ce; acc[A_CUBC] += (ok && okC) ? 1.f : 0.f; }
      else if (c == 3) { acc[A_REF_CUB_CE] += ce; acc[A_REF_CUBC] += ok ? 1.f : 0.f; }
      else if (c == 4) { acc[A_TR_CUB_CE]  += ce; acc[A_TR_CUBC]  += ok ? 1.f : 0.f; }
      else if (c == 5) { acc[A_SQ_CUB_CE] += ce; acc[A_SQ_CUBC] += (ok && okC && okD) ? 1.f : 0.f; }
    } else if (k == 2) {
      if (c == 2)      acc[A_CE_AP] += ce;
      else if (c == 5) acc[A_SQ_CUB_CE] += ce;
    } else if (k == 3) {
      if (c == 5) acc[A_SQ_CUB_CE] += ce;
    } else if (k == 5) {
      if (c == 3)      { acc[A_REF_AX_CE] += ce; acc[A_REF_AXC] += ok ? 1.f : 0.f; }
      else if (c == 4) { acc[A_TR_AX_CE]  += ce; acc[A_TR_AXC]  += ok ? 1.f : 0.f; }
    } else if (k == 6) {
      if (c == 5) { acc[A_FACE_CE] += ce; acc[A_FACEC] += ok ? 1.f : 0.f; }
    } else if (k == 7) {
      if (c == 1) {
        float x62 = pv[0], t62 = tv[0];
        float bce = -(POSW * t62 * logsig(x62) + (1.f - t62) * logsig(-x62));
        acc[A_BCE] += bce;
        bool pos = (t62 == 1.f), neg = (t62 == 0.f);
        acc[A_NPOS] += pos ? 1.f : 0.f;
        acc[A_NNEG] += neg ? 1.f : 0.f;
        acc[A_POSC] += (pos && x62 > 0.f) ? 1.f : 0.f;
        acc[A_NEGC] += (neg && x62 <= 0.f) ? 1.f : 0.f;
      }
    }
  }

  // ---- reduction: wave shuffle -> LDS -> atomics ----
  #pragma unroll
  for (int v = 0; v < NACC; ++v) {
    float x = acc[v];
    #pragma unroll
    for (int off = 32; off > 0; off >>= 1) x += __shfl_down(x, off, 64);
    if (lane == 0) sred[wave][v] = x;
  }
  {
    unsigned f = fl, m = mymin;
    #pragma unroll
    for (int off = 32; off > 0; off >>= 1) {
      f |= __shfl_down(f, off, 64);
      unsigned om = __shfl_down(m, off, 64);
      m = (om < m) ? om : m;
    }
    if (lane == 0) { sflags[wave] = f; smin[wave] = m; }
  }
  __syncthreads();
  unsigned* wu = (unsigned*)ws;
  if (tid == 0) {
    unsigned f = sflags[0] | sflags[1] | sflags[2] | sflags[3];
    unsigned m = min(min(smin[0], smin[1]), min(smin[2], smin[3]));
    if (f) atomicOr(&wu[NACC + 1], f);
    if (m != 0xFFFFFFFFu) atomicMin(&wu[NACC], m);
  }
  if (tid < NACC) {
    float s = sred[0][tid] + sred[1][tid] + sred[2][tid] + sred[3][tid];
    if (s != 0.f) atomicAdd(&ws[tid], s);
  }
}

__global__ void finalize_k(const float* __restrict__ ws,
                           const float* __restrict__ P,
                           const float* __restrict__ T,
                           float* __restrict__ out) {
  const unsigned* wu = (const unsigned*)ws;
  unsigned flags = wu[NACC + 1];
  unsigned fm = wu[NACC];
  bool g_cub  = (flags & F_CUB)  != 0;
  bool g_cub2 = (flags & F_CUB2) != 0;
  bool g_ap   = (flags & F_AP)   != 0;
  bool g_ref  = (flags & F_REF)  != 0;
  bool g_tr   = (flags & F_TR)   != 0;
  bool g_sq   = (flags & F_SQ)   != 0;
  unsigned first = (fm == 0xFFFFFFFFu) ? 0u : fm;
  float x62 = P[(size_t)first * D_COLS + 62];
  float t62 = T[(size_t)first * D_COLS + 62];
  float bce_f = -(POSW * t62 * logsig(x62) + (1.f - t62) * logsig(-x62));
  float pos_f  = (t62 == 1.f) ? 1.f : 0.f;
  float neg_f  = (t62 == 0.f) ? 1.f : 0.f;
  float posc_f = (t62 == 1.f && x62 > 0.f) ? 1.f : 0.f;
  float negc_f = (t62 == 0.f && x62 <= 0.f) ? 1.f : 0.f;

  out[0]  = ws[A_CMD_LOSS];
  out[1]  = g_cub ? ws[A_MAE1] : 0.f;
  out[2]  = g_ap  ? ws[A_MAE2] : 0.f;
  out[3]  = g_sq  ? ws[A_MAE5] : 0.f;
  out[4]  = g_tr  ? ws[A_MAE4] : 0.f;
  out[5]  = g_ap  ? ws[A_CE_AP] : 0.f;
  out[6]  = g_sq  ? ws[A_SQ_CUB_CE] : 0.f;
  out[7]  = (g_ref ? ws[A_REF_CUB_CE] : 0.f) + (g_tr ? ws[A_TR_CUB_CE] : 0.f);
  out[8]  = (g_ref ? ws[A_REF_AX_CE]  : 0.f) + (g_tr ? ws[A_TR_AX_CE]  : 0.f);
  out[9]  = g_sq ? ws[A_FACE_CE] : 0.f;
  out[10] = ws[A_CMDC];
  out[11] = g_ap ? ws[A_CUBC] : 0.f;
  out[12] = g_sq ? ws[A_SQ_CUBC] : 0.f;
  out[13] = (g_ref ? ws[A_REF_CUBC] : 0.f) + (g_tr ? ws[A_TR_CUBC] : 0.f);
  out[14] = (g_ref ? ws[A_REF_AXC]  : 0.f) + (g_tr ? ws[A_TR_AXC]  : 0.f);
  out[15] = g_sq ? ws[A_FACEC] : 0.f;
  out[16] = g_cub2 ? (ws[A_BCE]  - bce_f)  : 0.f;
  out[17] = g_cub2 ? (ws[A_POSC] - posc_f) : 0.f;
  out[18] = g_cub2 ? (ws[A_NEGC] - negc_f) : 0.f;
  out[19] = g_cub2 ? (ws[A_NNEG] - neg_f)  : 0.f;
  out[20] = g_cub2 ? (ws[A_NPOS] - pos_f)  : 0.f;
  out[21] = ws[A_NA];
  out[22] = ws[A_NC];
  out[23] = ws[A_NREF] + ws[A_NTR];
  out[24] = ws[A_NSQ];
}

extern "C" void kernel_launch(void* const* d_in, const int* in_sizes, int n_in,
                              void* d_out, int out_size, void* d_ws, size_t ws_size,
                              hipStream_t stream) {
  const float* P = (const float*)d_in[0];
  const float* T = (const float*)d_in[1];
  const float* W = (const float*)d_in[2];
  float* ws = (float*)d_ws;
  float* out = (float*)d_out;

  hipLaunchKernelGGL(init_ws, dim3(1), dim3(64), 0, stream, ws);
  hipLaunchKernelGGL(prog_loss_main, dim3(GRID), dim3(BLOCK), 0, stream, P, T, W, ws);
  hipLaunchKernelGGL(finalize_k, dim3(1), dim3(1), 0, stream, ws, P, T, out);
}